// Round 5
// baseline (835.055 us; speedup 1.0000x reference)
//
#include <hip/hip_runtime.h>
#include <hip/hip_bf16.h>
#include <cmath>

#define NNODES 100000
#define NEDGES 1600000
#define SCAN_B 1024

typedef __attribute__((ext_vector_type(8))) short bf16x8;
typedef __attribute__((ext_vector_type(4))) float f32x4;

// RNE fp32 -> bf16 (finite inputs)
__device__ __forceinline__ unsigned short f2bf(float f) {
    unsigned u = __builtin_bit_cast(unsigned, f);
    unsigned r = (u + 0x7fffu + ((u >> 16) & 1u)) >> 16;
    return (unsigned short)r;
}
__device__ __forceinline__ float bflo(unsigned v) {
    return __builtin_bit_cast(float, v << 16);
}
__device__ __forceinline__ float bfhi(unsigned v) {
    return __builtin_bit_cast(float, v & 0xffff0000u);
}

// ---------------- CSR build ----------------

__global__ void zero_deg(int* __restrict__ deg, int n) {
    int i = blockIdx.x * 256 + threadIdx.x;
    if (i < n) deg[i] = 0;
}

// XCD-partitioned degree count: group g (= blockIdx&7, round-robin XCD mapping)
// only processes edges whose dst lies in its 1/8 node range -> deg atomics stay
// in one XCD's L2.
__global__ __launch_bounds__(256) void count_deg_xcd(const int* __restrict__ dst,
                                                     int* __restrict__ deg, int E) {
    int g = blockIdx.x & 7;
    int sub = blockIdx.x >> 3;
    int nsub = gridDim.x >> 3;
    int lo = g * (NNODES / 8), hi = lo + (NNODES / 8);
    for (int e = sub * 256 + threadIdx.x; e < E; e += nsub * 256) {
        int d = dst[e];
        if (d >= lo && d < hi) atomicAdd(&deg[d], 1);
    }
}

__global__ void calc_dinv(const int* __restrict__ deg, float* __restrict__ dinv, int n) {
    int i = blockIdx.x * 256 + threadIdx.x;
    if (i < n) dinv[i] = rsqrtf(1.0f + (float)deg[i]);   // +1 self-loop
}

__global__ __launch_bounds__(SCAN_B) void scan_block(const int* __restrict__ deg,
                                                     int* __restrict__ pos,
                                                     int* __restrict__ bsums, int n) {
    __shared__ int s[SCAN_B];
    int tid = threadIdx.x;
    int gid = blockIdx.x * SCAN_B + tid;
    int v = (gid < n) ? deg[gid] : 0;
    s[tid] = v;
    __syncthreads();
    for (int off = 1; off < SCAN_B; off <<= 1) {
        int t = (tid >= off) ? s[tid - off] : 0;
        __syncthreads();
        s[tid] += t;
        __syncthreads();
    }
    if (gid < n) pos[gid] = s[tid] - v;          // exclusive
    if (tid == SCAN_B - 1) bsums[blockIdx.x] = s[tid];
}

__global__ __launch_bounds__(128) void scan_sums(int* __restrict__ bsums, int nb) {
    __shared__ int s[128];
    int tid = threadIdx.x;
    int v = (tid < nb) ? bsums[tid] : 0;
    s[tid] = v;
    __syncthreads();
    for (int off = 1; off < 128; off <<= 1) {
        int t = (tid >= off) ? s[tid - off] : 0;
        __syncthreads();
        s[tid] += t;
        __syncthreads();
    }
    if (tid < nb) bsums[tid] = s[tid] - v;       // exclusive
}

__global__ __launch_bounds__(SCAN_B) void add_off(int* __restrict__ pos,
                                                  const int* __restrict__ bsums, int n) {
    int gid = blockIdx.x * SCAN_B + threadIdx.x;
    if (gid < n) pos[gid] += bsums[blockIdx.x];
}

// XCD-partitioned CSR fill: each group's csr_src writes land in a contiguous
// ~800 KB slot range owned by one XCD -> lines fill completely in its L2
// before writeback (avg degree 16 -> one node == one 64B line).
// pos[] is mutated into end[] (end[i-1] == start[i]) as before.
__global__ __launch_bounds__(256) void csr_fill_xcd(const int* __restrict__ src,
                                                    const int* __restrict__ dst,
                                                    int* __restrict__ pos,
                                                    int* __restrict__ csr_src, int E) {
    int g = blockIdx.x & 7;
    int sub = blockIdx.x >> 3;
    int nsub = gridDim.x >> 3;
    int lo = g * (NNODES / 8), hi = lo + (NNODES / 8);
    for (int e = sub * 256 + threadIdx.x; e < E; e += nsub * 256) {
        int d = dst[e];
        if (d >= lo && d < hi) {
            int slot = atomicAdd(&pos[d], 1);
            csr_src[slot] = src[e];
        }
    }
}

// ---------------- weight convert ----------------

__global__ __launch_bounds__(256) void conv_w1t(const float* __restrict__ W1,
                                                unsigned short* __restrict__ W1t) {
    int t = blockIdx.x * 256 + threadIdx.x;      // 128*512
    if (t >= 128 * 512) return;
    int n = t >> 9, k = t & 511;
    W1t[t] = (k < 500) ? f2bf(W1[k * 128 + n]) : (unsigned short)0;
}

__global__ __launch_bounds__(256) void conv_w2t(const float* __restrict__ W2,
                                                unsigned short* __restrict__ W2t) {
    int t = blockIdx.x * 256 + threadIdx.x;      // 64*128
    if (t >= 64 * 128) return;
    int n = t >> 7, k = t & 127;
    W2t[t] = f2bf(W2[k * 64 + n]);
}

// ---------------- layer-1 MFMA GEMM: h1'[M,128](bf16) = dinv .* (x @ W1) ----------
// Depth-1 register prefetch + double-buffered LDS, rolling loop (one barrier
// per iteration). Global loads for tile it+1 issue before the MFMAs of tile
// it; their waitcnt lands at the LDS store after the MFMA block.

__global__ __launch_bounds__(256) void gemm1_mfma(
    const float* __restrict__ x, const unsigned short* __restrict__ W1t,
    const float* __restrict__ dinv, unsigned short* __restrict__ C, int M)
{
    __shared__ short sA[2][4096];   // [buf][4 kq][128 row][8]
    __shared__ short sB[2][4096];   // [buf][4 kq][128 col][8]
    const int tid = threadIdx.x;
    const int w = tid >> 6;
    const int l = tid & 63;
    const int lm = l & 15;
    const int q = l >> 4;
    const int row0 = blockIdx.x * 128;

    f32x4 acc[2][8];
    #pragma unroll
    for (int i = 0; i < 2; i++)
        #pragma unroll
        for (int j = 0; j < 8; j++) acc[i][j] = (f32x4){0.f, 0.f, 0.f, 0.f};

    // fixed per-rep addressing (rep0: b=tid, rep1: b=tid+256)
    int akq[2];
    const float* aptr[2];
    const unsigned short* bptr[2];
    #pragma unroll
    for (int rep = 0; rep < 2; rep++) {
        int b = tid + rep * 256;                 // 0..511
        akq[rep] = (b >> 7) * 8;                 // k sub-offset: 0,8,16,24
        int m = b & 127;
        int r = row0 + m; if (r >= M) r = M - 1;
        aptr[rep] = x + (size_t)r * 500;
        bptr[rep] = W1t + (size_t)(b & 127) * 512;
    }

    const float4 z4 = {0.f, 0.f, 0.f, 0.f};
    float4 u[2], v[2];
    bf16x8 bb[2];

    // prologue: load tile 0, stage into buf 0
    #pragma unroll
    for (int rep = 0; rep < 2; rep++) {
        int kb = akq[rep];
        u[rep] = *(const float4*)(aptr[rep] + kb);
        v[rep] = *(const float4*)(aptr[rep] + kb + 4);
        bb[rep] = *(const bf16x8*)(bptr[rep] + akq[rep]);
    }
    #pragma unroll
    for (int rep = 0; rep < 2; rep++) {
        int b = tid + rep * 256;
        bf16x8 o;
        o[0] = f2bf(u[rep].x); o[1] = f2bf(u[rep].y);
        o[2] = f2bf(u[rep].z); o[3] = f2bf(u[rep].w);
        o[4] = f2bf(v[rep].x); o[5] = f2bf(v[rep].y);
        o[6] = f2bf(v[rep].z); o[7] = f2bf(v[rep].w);
        *(bf16x8*)&sA[0][b * 8] = o;
        *(bf16x8*)&sB[0][b * 8] = bb[rep];
    }
    __syncthreads();

    for (int it = 0; it < 16; ++it) {
        const int cur = it & 1;
        const int nxt = cur ^ 1;
        const bool more = (it + 1 < 16);

        // issue global loads for tile it+1 (latency hidden by MFMAs below)
        if (more) {
            int k0 = (it + 1) * 32;
            #pragma unroll
            for (int rep = 0; rep < 2; rep++) {
                int kb = k0 + akq[rep];
                u[rep] = (kb + 4 <= 500) ? *(const float4*)(aptr[rep] + kb)     : z4;
                v[rep] = (kb + 8 <= 500) ? *(const float4*)(aptr[rep] + kb + 4) : z4;
                bb[rep] = *(const bf16x8*)(bptr[rep] + kb);
            }
        }

        // compute tile it from LDS[cur]
        {
            bf16x8 af[2], bfr[8];
            #pragma unroll
            for (int i = 0; i < 2; i++)
                af[i] = *(const bf16x8*)&sA[cur][(q * 128 + w * 32 + i * 16 + lm) * 8];
            #pragma unroll
            for (int j = 0; j < 8; j++)
                bfr[j] = *(const bf16x8*)&sB[cur][(q * 128 + j * 16 + lm) * 8];
            #pragma unroll
            for (int i = 0; i < 2; i++)
                #pragma unroll
                for (int j = 0; j < 8; j++)
                    acc[i][j] = __builtin_amdgcn_mfma_f32_16x16x32_bf16(af[i], bfr[j], acc[i][j], 0, 0, 0);
        }

        // stage tile it+1 into LDS[nxt]; one barrier per iteration.
        // Safe: every wave's COMPUTE(cur) precedes this barrier, and the next
        // overwrite of LDS[cur] happens only after it.
        if (more) {
            #pragma unroll
            for (int rep = 0; rep < 2; rep++) {
                int b = tid + rep * 256;
                bf16x8 o;
                o[0] = f2bf(u[rep].x); o[1] = f2bf(u[rep].y);
                o[2] = f2bf(u[rep].z); o[3] = f2bf(u[rep].w);
                o[4] = f2bf(v[rep].x); o[5] = f2bf(v[rep].y);
                o[6] = f2bf(v[rep].z); o[7] = f2bf(v[rep].w);
                *(bf16x8*)&sA[nxt][b * 8] = o;
                *(bf16x8*)&sB[nxt][b * 8] = bb[rep];
            }
            __syncthreads();
        }
    }

    // C/D layout: col = j*16 + lm, row = q*4 + reg (+ i*16 + w*32); pre-scale by dinv[row]
    #pragma unroll
    for (int i = 0; i < 2; i++) {
        #pragma unroll
        for (int reg = 0; reg < 4; reg++) {
            int grow = row0 + w * 32 + i * 16 + q * 4 + reg;
            if (grow < M) {
                float d = dinv[grow];
                #pragma unroll
                for (int j = 0; j < 8; j++)
                    C[(size_t)grow * 128 + j * 16 + lm] = f2bf(d * acc[i][j][reg]);
            }
        }
    }
}

// ---------------- layer-2 MFMA GEMM: h2'[M,64](bf16) = dinv .* (a1 @ W2) ----------

__global__ __launch_bounds__(256) void gemm2_mfma(
    const unsigned short* __restrict__ A, const unsigned short* __restrict__ Bt,
    const float* __restrict__ dinv, unsigned short* __restrict__ C, int M)
{
    __shared__ short sA[4096];
    __shared__ short sB[2048];
    const int tid = threadIdx.x;
    const int w = tid >> 6;
    const int l = tid & 63;
    const int lm = l & 15;
    const int q = l >> 4;
    const int row0 = blockIdx.x * 128;

    f32x4 acc[2][4];
    #pragma unroll
    for (int i = 0; i < 2; i++)
        #pragma unroll
        for (int j = 0; j < 4; j++) acc[i][j] = (f32x4){0.f, 0.f, 0.f, 0.f};

    for (int k0 = 0; k0 < 128; k0 += 32) {
        __syncthreads();
        #pragma unroll
        for (int rep = 0; rep < 2; rep++) {
            int b = tid + rep * 256;
            int qq = b >> 7, m = b & 127;
            int r = row0 + m; if (r >= M) r = M - 1;
            *(bf16x8*)&sA[b * 8] = *(const bf16x8*)(A + (size_t)r * 128 + k0 + qq * 8);
        }
        {
            int b = tid;
            int qq = b >> 6, n = b & 63;
            *(bf16x8*)&sB[b * 8] = *(const bf16x8*)(Bt + (size_t)n * 128 + k0 + qq * 8);
        }
        __syncthreads();
        bf16x8 af[2];
        #pragma unroll
        for (int i = 0; i < 2; i++)
            af[i] = *(const bf16x8*)&sA[(q * 128 + w * 32 + i * 16 + lm) * 8];
        bf16x8 bfr[4];
        #pragma unroll
        for (int j = 0; j < 4; j++)
            bfr[j] = *(const bf16x8*)&sB[(q * 64 + j * 16 + lm) * 8];
        #pragma unroll
        for (int i = 0; i < 2; i++)
            #pragma unroll
            for (int j = 0; j < 4; j++)
                acc[i][j] = __builtin_amdgcn_mfma_f32_16x16x32_bf16(af[i], bfr[j], acc[i][j], 0, 0, 0);
    }

    #pragma unroll
    for (int i = 0; i < 2; i++) {
        #pragma unroll
        for (int reg = 0; reg < 4; reg++) {
            int grow = row0 + w * 32 + i * 16 + q * 4 + reg;
            if (grow < M) {
                float d = dinv[grow];
                #pragma unroll
                for (int j = 0; j < 4; j++)
                    C[(size_t)grow * 64 + j * 16 + lm] = f2bf(d * acc[i][j][reg]);
            }
        }
    }
}

// ---------------- layer-3 GEMM: h3'[M,40](fp32) = dinv .* (relu(A+b2) @ W4) ----------------

__global__ __launch_bounds__(256) void gemm_n40(
    const float* __restrict__ A, const float* __restrict__ W,
    const float* __restrict__ bias, const float* __restrict__ dinv,
    float* __restrict__ C, int M)
{
    __shared__ float sA[32][65];
    __shared__ float sW[64][40];
    const int row0 = blockIdx.x * 32;
    for (int idx = threadIdx.x; idx < 64 * 40; idx += 256)
        sW[idx / 40][idx % 40] = W[idx];
    for (int idx = threadIdx.x; idx < 32 * 64; idx += 256) {
        int r = idx >> 6, k = idx & 63;
        int row = row0 + r;
        float v = 0.0f;
        if (row < M) v = fmaxf(A[(long)row * 64 + k] + bias[k], 0.0f);
        sA[r][k] = v;
    }
    __syncthreads();
    float acc[5] = {0, 0, 0, 0, 0};
    int rr[5], cc[5];
    #pragma unroll
    for (int j = 0; j < 5; j++) {
        int o = threadIdx.x + 256 * j;
        rr[j] = o / 40; cc[j] = o % 40;
    }
    for (int k = 0; k < 64; k++) {
        #pragma unroll
        for (int j = 0; j < 5; j++) acc[j] += sA[rr[j]][k] * sW[k][cc[j]];
    }
    #pragma unroll
    for (int j = 0; j < 5; j++) {
        int row = row0 + rr[j];
        if (row < M) C[(long)row * 40 + cc[j]] = dinv[row] * acc[j];
    }
}

// ---------------- CSR gather over pre-scaled bf16 h': out[i] = di*(h'[i] + sum h'[s]) ----
// optional fused +bias,relu,->bf16 epilogue

template<int F, bool OBF16>
__global__ __launch_bounds__(256) void gather_bf(
    const unsigned short* __restrict__ h, const float* __restrict__ dinv,
    const int* __restrict__ pos, const int* __restrict__ csr_src,
    void* __restrict__ outv, const float* __restrict__ bias, int n)
{
    constexpr int P = F / 2;
    unsigned t = blockIdx.x * 256u + threadIdx.x;
    unsigned node = t / P;
    unsigned p = t - node * P;
    if (node >= (unsigned)n) return;
    int e0 = node ? pos[node - 1] : 0;
    int e1 = pos[node];
    float di = dinv[node];
    unsigned sv = *(const unsigned*)(h + (size_t)node * F + 2 * p);
    float a0 = bflo(sv);
    float a1 = bfhi(sv);
    int j = e0;
    for (; j + 4 <= e1; j += 4) {
        int s0 = csr_src[j], s1 = csr_src[j + 1], s2 = csr_src[j + 2], s3 = csr_src[j + 3];
        unsigned v0 = *(const unsigned*)(h + (size_t)s0 * F + 2 * p);
        unsigned v1 = *(const unsigned*)(h + (size_t)s1 * F + 2 * p);
        unsigned v2 = *(const unsigned*)(h + (size_t)s2 * F + 2 * p);
        unsigned v3 = *(const unsigned*)(h + (size_t)s3 * F + 2 * p);
        a0 += bflo(v0) + bflo(v1) + bflo(v2) + bflo(v3);
        a1 += bfhi(v0) + bfhi(v1) + bfhi(v2) + bfhi(v3);
    }
    for (; j < e1; j++) {
        int s = csr_src[j];
        unsigned v = *(const unsigned*)(h + (size_t)s * F + 2 * p);
        a0 += bflo(v);
        a1 += bfhi(v);
    }
    a0 *= di; a1 *= di;
    if constexpr (OBF16) {
        a0 = fmaxf(a0 + bias[2 * p], 0.0f);
        a1 = fmaxf(a1 + bias[2 * p + 1], 0.0f);
        ((unsigned*)outv)[(size_t)node * P + p] =
            ((unsigned)f2bf(a1) << 16) | (unsigned)f2bf(a0);
    } else {
        float2 r; r.x = a0; r.y = a1;
        ((float2*)outv)[(size_t)node * P + p] = r;
    }
}

// ---------------- fp32 CSR gather over pre-scaled h' (layer 3, F=40) ----------------

template<int F>
__global__ __launch_bounds__(256) void gather_agg(
    const float* __restrict__ h, const float* __restrict__ dinv,
    const int* __restrict__ pos, const int* __restrict__ csr_src,
    float* __restrict__ out, int n)
{
    unsigned t = blockIdx.x * 256u + threadIdx.x;
    unsigned node = t / F;
    unsigned c = t - node * F;
    if (node >= (unsigned)n) return;
    int e0 = node ? pos[node - 1] : 0;
    int e1 = pos[node];
    float di = dinv[node];
    float acc = h[(size_t)node * F + c];
    int j = e0;
    for (; j + 4 <= e1; j += 4) {
        int s0 = csr_src[j], s1 = csr_src[j + 1], s2 = csr_src[j + 2], s3 = csr_src[j + 3];
        float v0 = h[(size_t)s0 * F + c];
        float v1 = h[(size_t)s1 * F + c];
        float v2 = h[(size_t)s2 * F + c];
        float v3 = h[(size_t)s3 * F + c];
        acc += v0 + v1 + v2 + v3;
    }
    for (; j < e1; j++) {
        int s = csr_src[j];
        acc += h[(size_t)s * F + c];
    }
    out[(size_t)node * F + c] = di * acc;
}

// ---------------- log_softmax over rows of 40 (one wave per row), in-place safe ----------------

__global__ __launch_bounds__(256) void logsoftmax40(const float* __restrict__ h,
                                                    const float* __restrict__ bias,
                                                    float* __restrict__ out, int n) {
    int wave = (blockIdx.x * 256 + threadIdx.x) >> 6;
    int lane = threadIdx.x & 63;
    if (wave >= n) return;
    float x = 0.0f, v = -INFINITY;
    if (lane < 40) { x = h[(long)wave * 40 + lane] + bias[lane]; v = x; }
    #pragma unroll
    for (int off = 32; off; off >>= 1) v = fmaxf(v, __shfl_xor(v, off, 64));
    float ex = (lane < 40) ? expf(x - v) : 0.0f;
    float s = ex;
    #pragma unroll
    for (int off = 32; off; off >>= 1) s += __shfl_xor(s, off, 64);
    if (lane < 40) out[(long)wave * 40 + lane] = x - v - logf(s);
}

// ---------------- launch ----------------

extern "C" void kernel_launch(void* const* d_in, const int* in_sizes, int n_in,
                              void* d_out, int out_size, void* d_ws, size_t ws_size,
                              hipStream_t stream) {
    const float* x  = (const float*)d_in[0];
    const int*   ei = (const int*)d_in[1];
    const float* W1 = (const float*)d_in[2];
    const float* b1 = (const float*)d_in[3];
    const float* W2 = (const float*)d_in[4];
    const float* b2 = (const float*)d_in[5];
    const float* W4 = (const float*)d_in[6];
    const float* b4 = (const float*)d_in[7];
    float* out = (float*)d_out;
    float* ws  = (float*)d_ws;

    const int N = NNODES, E = NEDGES;
    const int* src = ei;
    const int* dst = ei + E;

    // workspace layout (float offsets), with overlay reuse (~85 MB total):
    float*          dinv    = ws;                              // 100k
    int*            deg     = (int*)(ws + 100000);
    int*            pos     = (int*)(ws + 200000);
    int*            bsums   = (int*)(ws + 300000);
    int*            csr_src = (int*)(ws + 300200);             // 1.6M ints
    unsigned short* W1t     = (unsigned short*)(ws + 1900200);
    unsigned short* W2t     = (unsigned short*)(ws + 1933000);
    // region R1: h1' bf16 [N][128]; later h2' bf16 [N][64]
    unsigned short* h1      = (unsigned short*)(ws + 1937100);
    unsigned short* h2      = (unsigned short*)(ws + 1937100);
    // region R2: a1 bf16 [N][128]; later h3' fp32 [N][40]
    unsigned short* a1      = (unsigned short*)(ws + 8337100);
    float*          h3      = ws + 8337100;
    // region R3: a2 fp32 [N][64]
    float*          a2      = ws + 14737100;
    float*          a3      = out;

    const int nscan = (N + SCAN_B - 1) / SCAN_B;

    // ---- CSR build + norm ----
    zero_deg<<<(N + 255) / 256, 256, 0, stream>>>(deg, N);
    count_deg_xcd<<<1024, 256, 0, stream>>>(dst, deg, E);
    calc_dinv<<<(N + 255) / 256, 256, 0, stream>>>(deg, dinv, N);
    scan_block<<<nscan, SCAN_B, 0, stream>>>(deg, pos, bsums, N);
    scan_sums<<<1, 128, 0, stream>>>(bsums, nscan);
    add_off<<<nscan, SCAN_B, 0, stream>>>(pos, bsums, N);
    csr_fill_xcd<<<1024, 256, 0, stream>>>(src, dst, pos, csr_src, E);

    // ---- weights convert ----
    conv_w1t<<<(128 * 512 + 255) / 256, 256, 0, stream>>>(W1, W1t);
    conv_w2t<<<(64 * 128 + 255) / 256, 256, 0, stream>>>(W2, W2t);

    // ---- layer 1: h1' = dinv.*(x @ W1) ; a1(bf16) = relu(di*(h1'[i]+sum h1'[s]) + b1) ----
    gemm1_mfma<<<(N + 127) / 128, 256, 0, stream>>>(x, W1t, dinv, h1, N);
    {
        unsigned tot = (unsigned)N * 64u;
        gather_bf<128, true><<<(tot + 255) / 256, 256, 0, stream>>>(h1, dinv, pos, csr_src, a1, b1, N);
    }

    // ---- layer 2: h2' = dinv.*(a1 @ W2) ; a2(fp32) = di*(h2'[i]+sum h2'[s]) ----
    gemm2_mfma<<<(N + 127) / 128, 256, 0, stream>>>(a1, W2t, dinv, h2, N);
    {
        unsigned tot = (unsigned)N * 32u;
        gather_bf<64, false><<<(tot + 255) / 256, 256, 0, stream>>>(h2, dinv, pos, csr_src, a2, nullptr, N);
    }

    // ---- layer 3: h3' = dinv.*(relu(a2+b2) @ W4) ; a3 = di*(h3'[i]+sum h3'[s]) ----
    gemm_n40<<<(N + 31) / 32, 256, 0, stream>>>(a2, W4, b2, dinv, h3, N);
    {
        unsigned tot = (unsigned)N * 40u;
        gather_agg<40><<<(tot + 255) / 256, 256, 0, stream>>>(h3, dinv, pos, csr_src, a3, N);
    }

    // ---- log_softmax(a3 + b4) in place ----
    logsoftmax40<<<(N * 64 + 255) / 256, 256, 0, stream>>>(a3, b4, out, N);
}

// Round 6
// 761.233 us; speedup vs baseline: 1.0970x; 1.0970x over previous
//
#include <hip/hip_runtime.h>
#include <hip/hip_bf16.h>
#include <cmath>

#define NNODES 100000
#define NEDGES 1600000
#define SCAN_B 1024

// padded per-q LDS strides (shorts): +8 pad shifts banks across q-blocks
#define Q1STR 1032   // 128*8 + 8
#define QA2STR 1032  // 128*8 + 8
#define QB2STR 520   // 64*8 + 8

typedef __attribute__((ext_vector_type(8))) short bf16x8;
typedef __attribute__((ext_vector_type(4))) float f32x4;

// RNE fp32 -> bf16 (finite inputs)
__device__ __forceinline__ unsigned short f2bf(float f) {
    unsigned u = __builtin_bit_cast(unsigned, f);
    unsigned r = (u + 0x7fffu + ((u >> 16) & 1u)) >> 16;
    return (unsigned short)r;
}
__device__ __forceinline__ float bflo(unsigned v) {
    return __builtin_bit_cast(float, v << 16);
}
__device__ __forceinline__ float bfhi(unsigned v) {
    return __builtin_bit_cast(float, v & 0xffff0000u);
}

// ---------------- CSR build ----------------

__global__ void zero_deg(int* __restrict__ deg, int n) {
    int i = blockIdx.x * 256 + threadIdx.x;
    if (i < n) deg[i] = 0;
}

// XCD-partitioned degree count (verified R4): atomics stay in one XCD's L2.
__global__ __launch_bounds__(256) void count_deg_xcd(const int* __restrict__ dst,
                                                     int* __restrict__ deg, int E) {
    int g = blockIdx.x & 7;
    int sub = blockIdx.x >> 3;
    int nsub = gridDim.x >> 3;
    int lo = g * (NNODES / 8), hi = lo + (NNODES / 8);
    for (int e = sub * 256 + threadIdx.x; e < E; e += nsub * 256) {
        int d = dst[e];
        if (d >= lo && d < hi) atomicAdd(&deg[d], 1);
    }
}

__global__ void calc_dinv(const int* __restrict__ deg, float* __restrict__ dinv, int n) {
    int i = blockIdx.x * 256 + threadIdx.x;
    if (i < n) dinv[i] = rsqrtf(1.0f + (float)deg[i]);   // +1 self-loop
}

__global__ __launch_bounds__(SCAN_B) void scan_block(const int* __restrict__ deg,
                                                     int* __restrict__ pos,
                                                     int* __restrict__ bsums, int n) {
    __shared__ int s[SCAN_B];
    int tid = threadIdx.x;
    int gid = blockIdx.x * SCAN_B + tid;
    int v = (gid < n) ? deg[gid] : 0;
    s[tid] = v;
    __syncthreads();
    for (int off = 1; off < SCAN_B; off <<= 1) {
        int t = (tid >= off) ? s[tid - off] : 0;
        __syncthreads();
        s[tid] += t;
        __syncthreads();
    }
    if (gid < n) pos[gid] = s[tid] - v;          // exclusive
    if (tid == SCAN_B - 1) bsums[blockIdx.x] = s[tid];
}

__global__ __launch_bounds__(128) void scan_sums(int* __restrict__ bsums, int nb) {
    __shared__ int s[128];
    int tid = threadIdx.x;
    int v = (tid < nb) ? bsums[tid] : 0;
    s[tid] = v;
    __syncthreads();
    for (int off = 1; off < 128; off <<= 1) {
        int t = (tid >= off) ? s[tid - off] : 0;
        __syncthreads();
        s[tid] += t;
        __syncthreads();
    }
    if (tid < nb) bsums[tid] = s[tid] - v;       // exclusive
}

__global__ __launch_bounds__(SCAN_B) void add_off(int* __restrict__ pos,
                                                  const int* __restrict__ bsums, int n) {
    int gid = blockIdx.x * SCAN_B + threadIdx.x;
    if (gid < n) pos[gid] += bsums[blockIdx.x];
}

// XCD-partitioned CSR fill (verified R4).
__global__ __launch_bounds__(256) void csr_fill_xcd(const int* __restrict__ src,
                                                    const int* __restrict__ dst,
                                                    int* __restrict__ pos,
                                                    int* __restrict__ csr_src, int E) {
    int g = blockIdx.x & 7;
    int sub = blockIdx.x >> 3;
    int nsub = gridDim.x >> 3;
    int lo = g * (NNODES / 8), hi = lo + (NNODES / 8);
    for (int e = sub * 256 + threadIdx.x; e < E; e += nsub * 256) {
        int d = dst[e];
        if (d >= lo && d < hi) {
            int slot = atomicAdd(&pos[d], 1);
            csr_src[slot] = src[e];
        }
    }
}

// ---------------- weight convert ----------------

__global__ __launch_bounds__(256) void conv_w1t(const float* __restrict__ W1,
                                                unsigned short* __restrict__ W1t) {
    int t = blockIdx.x * 256 + threadIdx.x;      // 128*512
    if (t >= 128 * 512) return;
    int n = t >> 9, k = t & 511;
    W1t[t] = (k < 500) ? f2bf(W1[k * 128 + n]) : (unsigned short)0;
}

__global__ __launch_bounds__(256) void conv_w2t(const float* __restrict__ W2,
                                                unsigned short* __restrict__ W2t) {
    int t = blockIdx.x * 256 + threadIdx.x;      // 64*128
    if (t >= 64 * 128) return;
    int n = t >> 7, k = t & 127;
    W2t[t] = f2bf(W2[k * 64 + n]);
}

// ---------------- layer-1 MFMA GEMM: h1'[M,128](bf16) = dinv .* (x @ W1) ----------
// R4 single-buffer structure; staging remapped for intra-wave coalescing:
//   A: idx = tid+256p, row = idx>>3, kq4 = idx&7 -> lanes 0-7 read one row's
//      contiguous 128 B (16 lines/instr instead of 64).
//   B: idx = tid+256p, n = idx>>2, c = idx&3 -> lanes 0-3 read one col's 64 B.
// LDS q-blocks padded (+8 shorts) to avoid 4-way write conflicts.

__global__ __launch_bounds__(256) void gemm1_mfma(
    const float* __restrict__ x, const unsigned short* __restrict__ W1t,
    const float* __restrict__ dinv, unsigned short* __restrict__ C, int M)
{
    __shared__ short sA[4 * Q1STR];
    __shared__ short sB[4 * Q1STR];
    const int tid = threadIdx.x;
    const int w = tid >> 6;
    const int l = tid & 63;
    const int lm = l & 15;
    const int q = l >> 4;
    const int row0 = blockIdx.x * 128;

    f32x4 acc[2][8];
    #pragma unroll
    for (int i = 0; i < 2; i++)
        #pragma unroll
        for (int j = 0; j < 8; j++) acc[i][j] = (f32x4){0.f, 0.f, 0.f, 0.f};

    for (int k0 = 0; k0 < 512; k0 += 32) {
        __syncthreads();
        // A stage: 1024 float4-chunks (128 rows x 8 kq4), coalesced per 8-lane group
        #pragma unroll
        for (int p = 0; p < 4; p++) {
            int idx = tid + p * 256;
            int row = idx >> 3, kq4 = idx & 7;
            int r = row0 + row; if (r >= M) r = M - 1;
            int kb = k0 + kq4 * 4;
            float4 u = (kb + 4 <= 500) ? *(const float4*)(x + (size_t)r * 500 + kb)
                                       : (float4){0.f, 0.f, 0.f, 0.f};
            short4 o;
            o.x = (short)f2bf(u.x); o.y = (short)f2bf(u.y);
            o.z = (short)f2bf(u.z); o.w = (short)f2bf(u.w);
            *(short4*)&sA[(kq4 >> 1) * Q1STR + row * 8 + (kq4 & 1) * 4] = o;
        }
        // B stage: 512 bf16x8-chunks (128 cols x 4 c), coalesced per 4-lane group
        #pragma unroll
        for (int p = 0; p < 2; p++) {
            int idx = tid + p * 256;
            int n = idx >> 2, c = idx & 3;
            bf16x8 v = *(const bf16x8*)(W1t + (size_t)n * 512 + k0 + c * 8);
            *(bf16x8*)&sB[c * Q1STR + n * 8] = v;
        }
        __syncthreads();
        bf16x8 af[2];
        #pragma unroll
        for (int i = 0; i < 2; i++)
            af[i] = *(const bf16x8*)&sA[q * Q1STR + (w * 32 + i * 16 + lm) * 8];
        bf16x8 bfr[8];
        #pragma unroll
        for (int j = 0; j < 8; j++)
            bfr[j] = *(const bf16x8*)&sB[q * Q1STR + (j * 16 + lm) * 8];
        #pragma unroll
        for (int i = 0; i < 2; i++)
            #pragma unroll
            for (int j = 0; j < 8; j++)
                acc[i][j] = __builtin_amdgcn_mfma_f32_16x16x32_bf16(af[i], bfr[j], acc[i][j], 0, 0, 0);
    }

    // C/D layout: col = j*16 + lm, row = q*4 + reg (+ i*16 + w*32); pre-scale by dinv[row]
    #pragma unroll
    for (int i = 0; i < 2; i++) {
        #pragma unroll
        for (int reg = 0; reg < 4; reg++) {
            int grow = row0 + w * 32 + i * 16 + q * 4 + reg;
            if (grow < M) {
                float d = dinv[grow];
                #pragma unroll
                for (int j = 0; j < 8; j++)
                    C[(size_t)grow * 128 + j * 16 + lm] = f2bf(d * acc[i][j][reg]);
            }
        }
    }
}

// ---------------- layer-2 MFMA GEMM: h2'[M,64](bf16) = dinv .* (a1 @ W2) ----------
// Same coalesced-staging treatment.

__global__ __launch_bounds__(256) void gemm2_mfma(
    const unsigned short* __restrict__ A, const unsigned short* __restrict__ Bt,
    const float* __restrict__ dinv, unsigned short* __restrict__ C, int M)
{
    __shared__ short sA[4 * QA2STR];
    __shared__ short sB[4 * QB2STR];
    const int tid = threadIdx.x;
    const int w = tid >> 6;
    const int l = tid & 63;
    const int lm = l & 15;
    const int q = l >> 4;
    const int row0 = blockIdx.x * 128;

    f32x4 acc[2][4];
    #pragma unroll
    for (int i = 0; i < 2; i++)
        #pragma unroll
        for (int j = 0; j < 4; j++) acc[i][j] = (f32x4){0.f, 0.f, 0.f, 0.f};

    for (int k0 = 0; k0 < 128; k0 += 32) {
        __syncthreads();
        // A stage: 512 bf16x8 (128 rows x 4 c), lanes 0-3 read one row's 64 B
        #pragma unroll
        for (int p = 0; p < 2; p++) {
            int idx = tid + p * 256;
            int row = idx >> 2, c = idx & 3;
            int r = row0 + row; if (r >= M) r = M - 1;
            bf16x8 v = *(const bf16x8*)(A + (size_t)r * 128 + k0 + c * 8);
            *(bf16x8*)&sA[c * QA2STR + row * 8] = v;
        }
        // B stage: 256 bf16x8 (64 cols x 4 c)
        {
            int n = tid >> 2, c = tid & 3;
            bf16x8 v = *(const bf16x8*)(Bt + (size_t)n * 128 + k0 + c * 8);
            *(bf16x8*)&sB[c * QB2STR + n * 8] = v;
        }
        __syncthreads();
        bf16x8 af[2];
        #pragma unroll
        for (int i = 0; i < 2; i++)
            af[i] = *(const bf16x8*)&sA[q * QA2STR + (w * 32 + i * 16 + lm) * 8];
        bf16x8 bfr[4];
        #pragma unroll
        for (int j = 0; j < 4; j++)
            bfr[j] = *(const bf16x8*)&sB[q * QB2STR + (j * 16 + lm) * 8];
        #pragma unroll
        for (int i = 0; i < 2; i++)
            #pragma unroll
            for (int j = 0; j < 4; j++)
                acc[i][j] = __builtin_amdgcn_mfma_f32_16x16x32_bf16(af[i], bfr[j], acc[i][j], 0, 0, 0);
    }

    #pragma unroll
    for (int i = 0; i < 2; i++) {
        #pragma unroll
        for (int reg = 0; reg < 4; reg++) {
            int grow = row0 + w * 32 + i * 16 + q * 4 + reg;
            if (grow < M) {
                float d = dinv[grow];
                #pragma unroll
                for (int j = 0; j < 4; j++)
                    C[(size_t)grow * 64 + j * 16 + lm] = f2bf(d * acc[i][j][reg]);
            }
        }
    }
}

// ---------------- layer-3 GEMM: h3'[M,40](fp32) = dinv .* (relu(A+b2) @ W4) ----------------

__global__ __launch_bounds__(256) void gemm_n40(
    const float* __restrict__ A, const float* __restrict__ W,
    const float* __restrict__ bias, const float* __restrict__ dinv,
    float* __restrict__ C, int M)
{
    __shared__ float sA[32][65];
    __shared__ float sW[64][40];
    const int row0 = blockIdx.x * 32;
    for (int idx = threadIdx.x; idx < 64 * 40; idx += 256)
        sW[idx / 40][idx % 40] = W[idx];
    for (int idx = threadIdx.x; idx < 32 * 64; idx += 256) {
        int r = idx >> 6, k = idx & 63;
        int row = row0 + r;
        float v = 0.0f;
        if (row < M) v = fmaxf(A[(long)row * 64 + k] + bias[k], 0.0f);
        sA[r][k] = v;
    }
    __syncthreads();
    float acc[5] = {0, 0, 0, 0, 0};
    int rr[5], cc[5];
    #pragma unroll
    for (int j = 0; j < 5; j++) {
        int o = threadIdx.x + 256 * j;
        rr[j] = o / 40; cc[j] = o % 40;
    }
    for (int k = 0; k < 64; k++) {
        #pragma unroll
        for (int j = 0; j < 5; j++) acc[j] += sA[rr[j]][k] * sW[k][cc[j]];
    }
    #pragma unroll
    for (int j = 0; j < 5; j++) {
        int row = row0 + rr[j];
        if (row < M) C[(long)row * 40 + cc[j]] = dinv[row] * acc[j];
    }
}

// ---------------- CSR gather over pre-scaled bf16 h': out[i] = di*(h'[i] + sum h'[s]) ----
// optional fused +bias,relu,->bf16 epilogue

template<int F, bool OBF16>
__global__ __launch_bounds__(256) void gather_bf(
    const unsigned short* __restrict__ h, const float* __restrict__ dinv,
    const int* __restrict__ pos, const int* __restrict__ csr_src,
    void* __restrict__ outv, const float* __restrict__ bias, int n)
{
    constexpr int P = F / 2;
    unsigned t = blockIdx.x * 256u + threadIdx.x;
    unsigned node = t / P;
    unsigned p = t - node * P;
    if (node >= (unsigned)n) return;
    int e0 = node ? pos[node - 1] : 0;
    int e1 = pos[node];
    float di = dinv[node];
    unsigned sv = *(const unsigned*)(h + (size_t)node * F + 2 * p);
    float a0 = bflo(sv);
    float a1 = bfhi(sv);
    int j = e0;
    for (; j + 4 <= e1; j += 4) {
        int s0 = csr_src[j], s1 = csr_src[j + 1], s2 = csr_src[j + 2], s3 = csr_src[j + 3];
        unsigned v0 = *(const unsigned*)(h + (size_t)s0 * F + 2 * p);
        unsigned v1 = *(const unsigned*)(h + (size_t)s1 * F + 2 * p);
        unsigned v2 = *(const unsigned*)(h + (size_t)s2 * F + 2 * p);
        unsigned v3 = *(const unsigned*)(h + (size_t)s3 * F + 2 * p);
        a0 += bflo(v0) + bflo(v1) + bflo(v2) + bflo(v3);
        a1 += bfhi(v0) + bfhi(v1) + bfhi(v2) + bfhi(v3);
    }
    for (; j < e1; j++) {
        int s = csr_src[j];
        unsigned v = *(const unsigned*)(h + (size_t)s * F + 2 * p);
        a0 += bflo(v);
        a1 += bfhi(v);
    }
    a0 *= di; a1 *= di;
    if constexpr (OBF16) {
        a0 = fmaxf(a0 + bias[2 * p], 0.0f);
        a1 = fmaxf(a1 + bias[2 * p + 1], 0.0f);
        ((unsigned*)outv)[(size_t)node * P + p] =
            ((unsigned)f2bf(a1) << 16) | (unsigned)f2bf(a0);
    } else {
        float2 r; r.x = a0; r.y = a1;
        ((float2*)outv)[(size_t)node * P + p] = r;
    }
}

// ---------------- fp32 CSR gather over pre-scaled h' (layer 3, F=40) ----------------

template<int F>
__global__ __launch_bounds__(256) void gather_agg(
    const float* __restrict__ h, const float* __restrict__ dinv,
    const int* __restrict__ pos, const int* __restrict__ csr_src,
    float* __restrict__ out, int n)
{
    unsigned t = blockIdx.x * 256u + threadIdx.x;
    unsigned node = t / F;
    unsigned c = t - node * F;
    if (node >= (unsigned)n) return;
    int e0 = node ? pos[node - 1] : 0;
    int e1 = pos[node];
    float di = dinv[node];
    float acc = h[(size_t)node * F + c];
    int j = e0;
    for (; j + 4 <= e1; j += 4) {
        int s0 = csr_src[j], s1 = csr_src[j + 1], s2 = csr_src[j + 2], s3 = csr_src[j + 3];
        float v0 = h[(size_t)s0 * F + c];
        float v1 = h[(size_t)s1 * F + c];
        float v2 = h[(size_t)s2 * F + c];
        float v3 = h[(size_t)s3 * F + c];
        acc += v0 + v1 + v2 + v3;
    }
    for (; j < e1; j++) {
        int s = csr_src[j];
        acc += h[(size_t)s * F + c];
    }
    out[(size_t)node * F + c] = di * acc;
}

// ---------------- log_softmax over rows of 40 (one wave per row), in-place safe ----------------

__global__ __launch_bounds__(256) void logsoftmax40(const float* __restrict__ h,
                                                    const float* __restrict__ bias,
                                                    float* __restrict__ out, int n) {
    int wave = (blockIdx.x * 256 + threadIdx.x) >> 6;
    int lane = threadIdx.x & 63;
    if (wave >= n) return;
    float x = 0.0f, v = -INFINITY;
    if (lane < 40) { x = h[(long)wave * 40 + lane] + bias[lane]; v = x; }
    #pragma unroll
    for (int off = 32; off; off >>= 1) v = fmaxf(v, __shfl_xor(v, off, 64));
    float ex = (lane < 40) ? expf(x - v) : 0.0f;
    float s = ex;
    #pragma unroll
    for (int off = 32; off; off >>= 1) s += __shfl_xor(s, off, 64);
    if (lane < 40) out[(long)wave * 40 + lane] = x - v - logf(s);
}

// ---------------- launch ----------------

extern "C" void kernel_launch(void* const* d_in, const int* in_sizes, int n_in,
                              void* d_out, int out_size, void* d_ws, size_t ws_size,
                              hipStream_t stream) {
    const float* x  = (const float*)d_in[0];
    const int*   ei = (const int*)d_in[1];
    const float* W1 = (const float*)d_in[2];
    const float* b1 = (const float*)d_in[3];
    const float* W2 = (const float*)d_in[4];
    const float* b2 = (const float*)d_in[5];
    const float* W4 = (const float*)d_in[6];
    const float* b4 = (const float*)d_in[7];
    float* out = (float*)d_out;
    float* ws  = (float*)d_ws;

    const int N = NNODES, E = NEDGES;
    const int* src = ei;
    const int* dst = ei + E;

    // workspace layout (float offsets), with overlay reuse (~85 MB total):
    float*          dinv    = ws;                              // 100k
    int*            deg     = (int*)(ws + 100000);
    int*            pos     = (int*)(ws + 200000);
    int*            bsums   = (int*)(ws + 300000);
    int*            csr_src = (int*)(ws + 300200);             // 1.6M ints
    unsigned short* W1t     = (unsigned short*)(ws + 1900200);
    unsigned short* W2t     = (unsigned short*)(ws + 1933000);
    // region R1: h1' bf16 [N][128]; later h2' bf16 [N][64]
    unsigned short* h1      = (unsigned short*)(ws + 1937100);
    unsigned short* h2      = (unsigned short*)(ws + 1937100);
    // region R2: a1 bf16 [N][128]; later h3' fp32 [N][40]
    unsigned short* a1      = (unsigned short*)(ws + 8337100);
    float*          h3      = ws + 8337100;
    // region R3: a2 fp32 [N][64]
    float*          a2      = ws + 14737100;
    float*          a3      = out;

    const int nscan = (N + SCAN_B - 1) / SCAN_B;

    // ---- CSR build + norm ----
    zero_deg<<<(N + 255) / 256, 256, 0, stream>>>(deg, N);
    count_deg_xcd<<<1024, 256, 0, stream>>>(dst, deg, E);
    calc_dinv<<<(N + 255) / 256, 256, 0, stream>>>(deg, dinv, N);
    scan_block<<<nscan, SCAN_B, 0, stream>>>(deg, pos, bsums, N);
    scan_sums<<<1, 128, 0, stream>>>(bsums, nscan);
    add_off<<<nscan, SCAN_B, 0, stream>>>(pos, bsums, N);
    csr_fill_xcd<<<1024, 256, 0, stream>>>(src, dst, pos, csr_src, E);

    // ---- weights convert ----
    conv_w1t<<<(128 * 512 + 255) / 256, 256, 0, stream>>>(W1, W1t);
    conv_w2t<<<(64 * 128 + 255) / 256, 256, 0, stream>>>(W2, W2t);

    // ---- layer 1: h1' = dinv.*(x @ W1) ; a1(bf16) = relu(di*(h1'[i]+sum h1'[s]) + b1) ----
    gemm1_mfma<<<(N + 127) / 128, 256, 0, stream>>>(x, W1t, dinv, h1, N);
    {
        unsigned tot = (unsigned)N * 64u;
        gather_bf<128, true><<<(tot + 255) / 256, 256, 0, stream>>>(h1, dinv, pos, csr_src, a1, b1, N);
    }

    // ---- layer 2: h2' = dinv.*(a1 @ W2) ; a2(fp32) = di*(h2'[i]+sum h2'[s]) ----
    gemm2_mfma<<<(N + 127) / 128, 256, 0, stream>>>(a1, W2t, dinv, h2, N);
    {
        unsigned tot = (unsigned)N * 32u;
        gather_bf<64, false><<<(tot + 255) / 256, 256, 0, stream>>>(h2, dinv, pos, csr_src, a2, nullptr, N);
    }

    // ---- layer 3: h3' = dinv.*(relu(a2+b2) @ W4) ; a3 = di*(h3'[i]+sum h3'[s]) ----
    gemm_n40<<<(N + 31) / 32, 256, 0, stream>>>(a2, W4, b2, dinv, h3, N);
    {
        unsigned tot = (unsigned)N * 40u;
        gather_agg<40><<<(tot + 255) / 256, 256, 0, stream>>>(h3, dinv, pos, csr_src, a3, N);
    }

    // ---- log_softmax(a3 + b4) in place ----
    logsoftmax40<<<(N * 64 + 255) / 256, 256, 0, stream>>>(a3, b4, out, N);
}